// Round 1
// baseline (435.966 us; speedup 1.0000x reference)
//
#include <hip/hip_runtime.h>

// X [B, N, D] fp32, mask [B, N] int (1 = masked OUT), W [D], b [D].
// B=64, N=8192, D=128. REPLACE = 0.0 -> masked rows output b[d].
#define B_ 64
#define N_ 8192
#define D_ 128
#define D4 (D_ / 4)            // 32 float4 per row
#define NCHUNKS 32
#define CHUNK (N_ / NCHUNKS)   // 256 rows per reduce block

// Native vector type: __builtin_nontemporal_store requires it (HIP float4 class is rejected).
typedef float v4f __attribute__((ext_vector_type(4)));

// Workspace layout (floats) — every slot fully written before read, no init needed:
//  [WS_SUMP,  +B*NCHUNKS*D)   per-(b,chunk) partial sums
//  [WS_SQP,   +B*NCHUNKS*D)   per-(b,chunk) partial sum-of-squares
//  [WS_CNTP,  +B*NCHUNKS)     per-(b,chunk) valid-row counts
//  [WS_SCALE, +B*D)           W*rsqrt(var)
//  [WS_SHIFT, +B*D)           b - mean*scale
#define WS_SUMP  0
#define WS_SQP   (B_ * NCHUNKS * D_)
#define WS_CNTP  (2 * B_ * NCHUNKS * D_)
#define WS_SCALE (2 * B_ * NCHUNKS * D_ + B_ * NCHUNKS)
#define WS_SHIFT (WS_SCALE + B_ * D_)

__global__ __launch_bounds__(256) void reduce_kernel(
        const float* __restrict__ X, const int* __restrict__ mask,
        float* __restrict__ ws) {
    const int b   = blockIdx.x;
    const int cy  = blockIdx.y;
    const int tid = threadIdx.x;
    const int q   = tid & 31;   // float4 column within row
    const int sub = tid >> 5;   // 0..7 row phase
    const int n0  = cy * CHUNK;

    // Preload this chunk's mask into LDS as 0/1 floats: removes the global
    // mask load -> X load dependency from the hot loop entirely.
    __shared__ float valid[CHUNK];
    valid[tid] = (mask[b * N_ + n0 + tid] == 0) ? 1.0f : 0.0f;
    __syncthreads();

    const v4f* __restrict__ Xr =
        (const v4f*)(X + (size_t)b * N_ * D_) + (size_t)n0 * D4 + q;

    v4f s  = (v4f)(0.f);
    v4f ss = (v4f)(0.f);
    float cnt = 0.f;

    // Branch-skip masked rows: a masked row is 512 contiguous bytes that are
    // then never fetched from HBM (~50% fetch saved).
    #pragma unroll
    for (int k = 0; k < CHUNK / 8; ++k) {      // 32 iterations
        const int n = sub + 8 * k;
        const float v = valid[n];              // LDS broadcast across q lanes
        cnt += v;
        if (v != 0.0f) {
            const v4f x = Xr[(size_t)n * D4];
            s += x;
            ss += x * x;
        }
    }

    __shared__ v4f sh_s[8][32];
    __shared__ v4f sh_ss[8][32];
    __shared__ float sh_c[8];
    sh_s[sub][q]  = s;
    sh_ss[sub][q] = ss;
    if (q == 0) sh_c[sub] = cnt;
    __syncthreads();

    if (sub == 0) {
        v4f ts = s, tss = ss;
        #pragma unroll
        for (int k = 1; k < 8; ++k) {
            ts  += sh_s[k][q];
            tss += sh_ss[k][q];
        }
        v4f* __restrict__ sump = (v4f*)(ws + WS_SUMP);
        v4f* __restrict__ sqp  = (v4f*)(ws + WS_SQP);
        const int slot = (b * NCHUNKS + cy) * D4 + q;
        sump[slot] = ts;
        sqp[slot]  = tss;
    }
    if (tid == 0) {
        float c = 0.f;
        #pragma unroll
        for (int k = 0; k < 8; ++k) c += sh_c[k];
        ws[WS_CNTP + b * NCHUNKS + cy] = c;
    }
}

__global__ __launch_bounds__(256) void finalize_kernel(
        const float* __restrict__ W, const float* __restrict__ bias,
        float* __restrict__ ws) {
    const float* __restrict__ sump = ws + WS_SUMP;
    const float* __restrict__ sqp  = ws + WS_SQP;
    const float* __restrict__ cntp = ws + WS_CNTP;
    float* __restrict__ scale = ws + WS_SCALE;
    float* __restrict__ shift = ws + WS_SHIFT;

    const int i = blockIdx.x * blockDim.x + threadIdx.x;   // 0 .. B*D
    if (i >= B_ * D_) return;
    const int b = i >> 7;          // / D_
    const int d = i & (D_ - 1);

    float c = 0.f, s = 0.f, sq = 0.f;
    #pragma unroll
    for (int cy = 0; cy < NCHUNKS; ++cy) {
        c  += cntp[b * NCHUNKS + cy];
        s  += sump[(b * NCHUNKS + cy) * D_ + d];
        sq += sqp [(b * NCHUNKS + cy) * D_ + d];
    }
    const float mean = s / c;
    const float var  = (sq - s * mean) / (c - 1.0f);   // unbiased
    const float sc   = W[d] * rsqrtf(var);
    scale[i] = sc;
    shift[i] = bias[d] - mean * sc;
}

__global__ __launch_bounds__(256) void normalize_kernel(
        const float* __restrict__ X, const int* __restrict__ mask,
        const float* __restrict__ ws, const float* __restrict__ bias,
        float* __restrict__ out) {
    const v4f* __restrict__ X4 = (const v4f*)X;
    v4f* __restrict__ O4 = (v4f*)out;
    const v4f* __restrict__ S4 = (const v4f*)(ws + WS_SCALE);
    const v4f* __restrict__ H4 = (const v4f*)(ws + WS_SHIFT);
    const v4f* __restrict__ B4 = (const v4f*)bias;

    // One thread per float4: no loop, maximal memory-level parallelism.
    const int i   = blockIdx.x * 256 + threadIdx.x;   // float4 index, < 2^24
    const int row = i >> 5;          // / D4
    const int c   = i & 31;
    const int b   = row >> 13;       // / N_

    if (mask[row] != 0) {
        // Masked row: output b[d]; X never fetched (saves ~50% of the re-read).
        __builtin_nontemporal_store(B4[c], &O4[i]);
    } else {
        const v4f x  = X4[i];
        const v4f sc = S4[(b << 5) + c];
        const v4f sh = H4[(b << 5) + c];
        __builtin_nontemporal_store(x * sc + sh, &O4[i]);
    }
}

extern "C" void kernel_launch(void* const* d_in, const int* in_sizes, int n_in,
                              void* d_out, int out_size, void* d_ws, size_t ws_size,
                              hipStream_t stream) {
    const float* X    = (const float*)d_in[0];
    const int*   mask = (const int*)d_in[1];
    const float* W    = (const float*)d_in[2];
    const float* bias = (const float*)d_in[3];
    float* out = (float*)d_out;
    float* ws  = (float*)d_ws;

    // 1) per-(batch, chunk) partial sums / sumsq / counts (no atomics, mask in LDS)
    reduce_kernel<<<dim3(B_, NCHUNKS), 256, 0, stream>>>(X, mask, ws);

    // 2) mean/var -> scale/shift
    finalize_kernel<<<(B_ * D_ + 255) / 256, 256, 0, stream>>>(W, bias, ws);

    // 3) elementwise normalize + affine + mask-replace (branch skips X fetch on masked rows)
    normalize_kernel<<<(B_ * N_ * D4) / 256, 256, 0, stream>>>(X, mask, ws, bias, out);
}

// Round 2
// 435.592 us; speedup vs baseline: 1.0009x; 1.0009x over previous
//
#include <hip/hip_runtime.h>
#include <hip/hip_cooperative_groups.h>

namespace cg = cooperative_groups;

// X [B, N, D] fp32, mask [B, N] int (1 = masked OUT), W [D], b [D].
// B=64, N=8192, D=128. REPLACE = 0.0 -> masked rows output b[d].
#define B_ 64
#define N_ 8192
#define D_ 128
#define D4 (D_ / 4)            // 32 float4 per row

typedef float v4f __attribute__((ext_vector_type(4)));

// ---------------- fused cooperative path ----------------
#define NCH 16
#define CHROWS (N_ / NCH)      // 512 rows per block

// fused ws layout (floats); every slot written before read
#define FW_SUM 0                        // B*NCH*D
#define FW_SQ  (B_ * NCH * D_)          // B*NCH*D
#define FW_CNT (2 * B_ * NCH * D_)      // B*NCH

__global__ __launch_bounds__(256, 4) void fused_kernel(
        const float* __restrict__ X, const int* __restrict__ mask,
        const float* __restrict__ W, const float* __restrict__ bias,
        float* __restrict__ out, float* __restrict__ ws) {
    const int b   = blockIdx.x;
    const int cy  = blockIdx.y;
    const int tid = threadIdx.x;
    const int q   = tid & 31;   // float4 column within row
    const int sub = tid >> 5;   // 0..7 row phase
    const int n0  = cy * CHROWS;

    __shared__ unsigned long long wmask[8];     // ballot per 64-row group
    __shared__ unsigned short rows[CHROWS];     // compacted valid rows
    __shared__ unsigned short mrows[CHROWS];    // compacted masked rows
    __shared__ v4f sh_s[8][32];
    __shared__ v4f sh_ss[8][32];
    __shared__ v4f sc4[D4], sh4[D4], b4[D4];

    // ---- ballot-compact valid & masked row lists (rows tid and tid+256) ----
    const int lane = tid & 63;
    const int wv   = tid >> 6;                  // wave id 0..3
    const int m0 = mask[b * N_ + n0 + tid];
    const int m1 = mask[b * N_ + n0 + 256 + tid];
    const unsigned long long bal0 = __ballot(m0 == 0);
    const unsigned long long bal1 = __ballot(m1 == 0);
    if (lane == 0) { wmask[wv] = bal0; wmask[wv + 4] = bal1; }
    __syncthreads();
    int pre[8];
    int acc = 0;
    #pragma unroll
    for (int g = 0; g < 8; ++g) { pre[g] = acc; acc += __popcll(wmask[g]); }
    const int nvalid = acc;                     // valid rows in this chunk
    {
        const unsigned long long below = (1ull << lane) - 1ull;
        const int rv0 = pre[wv] + __popcll(bal0 & below);
        if (m0 == 0) rows[rv0] = (unsigned short)tid;
        else         mrows[tid - rv0] = (unsigned short)tid;
        const int j1 = tid + 256;
        const int rv1 = pre[wv + 4] + __popcll(bal1 & below);
        if (m1 == 0) rows[rv1] = (unsigned short)j1;
        else         mrows[j1 - rv1] = (unsigned short)j1;
    }
    __syncthreads();

    const v4f* __restrict__ Xr = (const v4f*)(X + ((size_t)b * N_ + n0) * D_) + q;
    v4f*       __restrict__ Or = (v4f*)(out + ((size_t)b * N_ + n0) * D_) + q;

    // ---- pass 1: sum / sumsq over compacted valid rows (full-lane loads) ----
    v4f s = (v4f)(0.f), ss = (v4f)(0.f);
    const int nmain = nvalid & ~7;
    #pragma unroll 4
    for (int j = sub; j < nmain; j += 8) {
        const int row = rows[j];
        const v4f x = Xr[(size_t)row * D4];
        s += x; ss += x * x;
    }
    if (nmain + sub < nvalid) {                 // tail (<8 rows)
        const int row = rows[nmain + sub];
        const v4f x = Xr[(size_t)row * D4];
        s += x; ss += x * x;
    }

    sh_s[sub][q] = s; sh_ss[sub][q] = ss;
    __syncthreads();
    if (sub == 0) {
        v4f ts = s, tss = ss;
        #pragma unroll
        for (int k = 1; k < 8; ++k) { ts += sh_s[k][q]; tss += sh_ss[k][q]; }
        ((v4f*)(ws + FW_SUM))[(b * NCH + cy) * D4 + q] = ts;
        ((v4f*)(ws + FW_SQ ))[(b * NCH + cy) * D4 + q] = tss;
    }
    if (tid == 0) ws[FW_CNT + b * NCH + cy] = (float)nvalid;

    cg::this_grid().sync();

    // ---- finalize: each block redundantly computes scale/shift for its b ----
    if (tid < D_) {
        const int d = tid;
        float c = 0.f, su = 0.f, sq = 0.f;
        #pragma unroll
        for (int k = 0; k < NCH; ++k) {
            c  += ws[FW_CNT + b * NCH + k];
            su += ws[FW_SUM + (b * NCH + k) * D_ + d];
            sq += ws[FW_SQ  + (b * NCH + k) * D_ + d];
        }
        const float mean = su / c;
        const float var  = (sq - su * mean) / (c - 1.0f);   // unbiased
        const float scv  = W[d] * rsqrtf(var);
        ((float*)sc4)[d] = scv;
        ((float*)sh4)[d] = bias[d] - mean * scv;
    }
    if (tid < D4) b4[tid] = ((const v4f*)bias)[tid];
    __syncthreads();

    // ---- pass 2: normalize valid rows (L3-resident re-read), bias-fill masked ----
    const v4f scq = sc4[q], shq = sh4[q], bq = b4[q];
    #pragma unroll 4
    for (int j = sub; j < nvalid; j += 8) {
        const int row = rows[j];
        const v4f x = Xr[(size_t)row * D4];
        __builtin_nontemporal_store(x * scq + shq, &Or[(size_t)row * D4]);
    }
    const int nmask = CHROWS - nvalid;
    #pragma unroll 4
    for (int j = sub; j < nmask; j += 8) {
        const int row = mrows[j];
        __builtin_nontemporal_store(bq, &Or[(size_t)row * D4]);
    }
}

// ---------------- fallback 3-kernel path (proven @436us) ----------------
#define NCHUNKS 32
#define CHUNK (N_ / NCHUNKS)
#define WS_SUMP  0
#define WS_SQP   (B_ * NCHUNKS * D_)
#define WS_CNTP  (2 * B_ * NCHUNKS * D_)
#define WS_SCALE (2 * B_ * NCHUNKS * D_ + B_ * NCHUNKS)
#define WS_SHIFT (WS_SCALE + B_ * D_)

__global__ __launch_bounds__(256) void reduce_kernel(
        const float* __restrict__ X, const int* __restrict__ mask,
        float* __restrict__ ws) {
    const int b   = blockIdx.x;
    const int cy  = blockIdx.y;
    const int tid = threadIdx.x;
    const int q   = tid & 31;
    const int sub = tid >> 5;
    const int n0  = cy * CHUNK;

    __shared__ float valid[CHUNK];
    valid[tid] = (mask[b * N_ + n0 + tid] == 0) ? 1.0f : 0.0f;
    __syncthreads();

    const v4f* __restrict__ Xr =
        (const v4f*)(X + (size_t)b * N_ * D_) + (size_t)n0 * D4 + q;

    v4f s  = (v4f)(0.f);
    v4f ss = (v4f)(0.f);
    float cnt = 0.f;
    #pragma unroll
    for (int k = 0; k < CHUNK / 8; ++k) {
        const int n = sub + 8 * k;
        const float v = valid[n];
        cnt += v;
        if (v != 0.0f) {
            const v4f x = Xr[(size_t)n * D4];
            s += x;
            ss += x * x;
        }
    }

    __shared__ v4f sh_s[8][32];
    __shared__ v4f sh_ss[8][32];
    __shared__ float sh_c[8];
    sh_s[sub][q]  = s;
    sh_ss[sub][q] = ss;
    if (q == 0) sh_c[sub] = cnt;
    __syncthreads();

    if (sub == 0) {
        v4f ts = s, tss = ss;
        #pragma unroll
        for (int k = 1; k < 8; ++k) {
            ts  += sh_s[k][q];
            tss += sh_ss[k][q];
        }
        ((v4f*)(ws + WS_SUMP))[(b * NCHUNKS + cy) * D4 + q] = ts;
        ((v4f*)(ws + WS_SQP ))[(b * NCHUNKS + cy) * D4 + q] = tss;
    }
    if (tid == 0) {
        float c = 0.f;
        #pragma unroll
        for (int k = 0; k < 8; ++k) c += sh_c[k];
        ws[WS_CNTP + b * NCHUNKS + cy] = c;
    }
}

__global__ __launch_bounds__(256) void finalize_kernel(
        const float* __restrict__ W, const float* __restrict__ bias,
        float* __restrict__ ws) {
    const int i = blockIdx.x * blockDim.x + threadIdx.x;
    if (i >= B_ * D_) return;
    const int b = i >> 7;
    const int d = i & (D_ - 1);

    float c = 0.f, s = 0.f, sq = 0.f;
    #pragma unroll
    for (int cy = 0; cy < NCHUNKS; ++cy) {
        c  += ws[WS_CNTP + b * NCHUNKS + cy];
        s  += ws[WS_SUMP + (b * NCHUNKS + cy) * D_ + d];
        sq += ws[WS_SQP  + (b * NCHUNKS + cy) * D_ + d];
    }
    const float mean = s / c;
    const float var  = (sq - s * mean) / (c - 1.0f);
    const float sc   = W[d] * rsqrtf(var);
    ws[WS_SCALE + i] = sc;
    ws[WS_SHIFT + i] = bias[d] - mean * sc;
}

__global__ __launch_bounds__(256) void normalize_kernel(
        const float* __restrict__ X, const int* __restrict__ mask,
        const float* __restrict__ ws, const float* __restrict__ bias,
        float* __restrict__ out) {
    const v4f* __restrict__ X4 = (const v4f*)X;
    v4f* __restrict__ O4 = (v4f*)out;
    const v4f* __restrict__ S4 = (const v4f*)(ws + WS_SCALE);
    const v4f* __restrict__ H4 = (const v4f*)(ws + WS_SHIFT);
    const v4f* __restrict__ B4 = (const v4f*)bias;

    const int i   = blockIdx.x * 256 + threadIdx.x;
    const int row = i >> 5;
    const int c   = i & 31;
    const int b   = row >> 13;

    if (mask[row] != 0) {
        __builtin_nontemporal_store(B4[c], &O4[i]);
    } else {
        const v4f x  = X4[i];
        const v4f sc = S4[(b << 5) + c];
        const v4f sh = H4[(b << 5) + c];
        __builtin_nontemporal_store(x * sc + sh, &O4[i]);
    }
}

extern "C" void kernel_launch(void* const* d_in, const int* in_sizes, int n_in,
                              void* d_out, int out_size, void* d_ws, size_t ws_size,
                              hipStream_t stream) {
    const float* X    = (const float*)d_in[0];
    const int*   mask = (const int*)d_in[1];
    const float* W    = (const float*)d_in[2];
    const float* bias = (const float*)d_in[3];
    float* out = (float*)d_out;
    float* ws  = (float*)d_ws;

    // one-time co-residency check for the cooperative path
    static int coop_ok = -1;
    if (coop_ok < 0) {
        int maxb = 0;
        hipError_t e1 = hipOccupancyMaxActiveBlocksPerMultiprocessor(
            &maxb, fused_kernel, 256, 0);
        int nCU = 256;
        hipDeviceProp_t prop;
        int dev = 0;
        if (hipGetDevice(&dev) == hipSuccess &&
            hipGetDeviceProperties(&prop, dev) == hipSuccess)
            nCU = prop.multiProcessorCount;
        coop_ok = (e1 == hipSuccess && maxb * nCU >= B_ * NCH) ? 1 : 0;
    }

    if (coop_ok == 1) {
        void* args[] = {(void*)&X, (void*)&mask, (void*)&W, (void*)&bias,
                        (void*)&out, (void*)&ws};
        hipError_t e = hipLaunchCooperativeKernel(
            (const void*)fused_kernel, dim3(B_, NCH), dim3(256), args, 0, stream);
        if (e == hipSuccess) return;
        coop_ok = 0;   // capture- or launch-incompatible: fall through
    }

    reduce_kernel<<<dim3(B_, NCHUNKS), 256, 0, stream>>>(X, mask, ws);
    finalize_kernel<<<(B_ * D_ + 255) / 256, 256, 0, stream>>>(W, bias, ws);
    normalize_kernel<<<(B_ * N_ * D4) / 256, 256, 0, stream>>>(X, mask, ws, bias, out);
}